// Round 16
// baseline (3277.773 us; speedup 1.0000x reference)
//
#include <hip/hip_runtime.h>
#include <hip/hip_bf16.h>

// ---------------- problem constants ----------------
#define BSZ 2
#define LSEQ 2048
#define DIM 1024
#define VOCAB 32000
#define NLAYER 4
#define DSTATE 128
#define DCONV 4
#define HEADDIM 64
#define DIN 2048
#define NH 32
#define CONVDIM 2304          // DIN + 2*DSTATE
#define DPROJ 4384            // 2*DIN + 2*DSTATE + NH
#define FFN 4096
#define QLEN 128
#define NTOK 4096             // BSZ*LSEQ
#define NCHUNK 32             // NTOK/QLEN
#define CPB 16                // chunks per batch
#define DTOFF 4352            // DIN + CONVDIM

#define SMEM3 98304           // gemm_p3: 3 x (A 16KB + B 16KB)
#define SMEM2 131072          // gemm_uv2: 2 x (A 32KB + B 32KB)

using f32x4 = __attribute__((ext_vector_type(4))) float;
using f16   = _Float16;
using f16x4 = __attribute__((ext_vector_type(4))) _Float16;
using f16x8 = __attribute__((ext_vector_type(8))) _Float16;

__device__ __forceinline__ void gld16(const void* g, void* l) {
  __builtin_amdgcn_global_load_lds(
      (const __attribute__((address_space(1))) unsigned int*)g,
      (__attribute__((address_space(3))) unsigned int*)l, 16, 0, 0);
}

// Tile swizzle: XCD-contiguous + column-chunked
__device__ __forceinline__ void swz_tiles(int& bx, int& by) {
  const int nx = gridDim.x, ny = gridDim.y;
  const int nwg = nx * ny;
  int bid = blockIdx.y * nx + blockIdx.x;
  if ((nwg & 7) == 0) bid = (bid & 7) * (nwg >> 3) + (bid >> 3);
  const int CW = 8;
  const int nchx = nx / CW;
  const int per = CW * ny;
  const int ch = bid / per;
  if (ch < nchx) {
    int wi = bid - ch * per;
    bx = ch * CW + (wi & (CW - 1));
    by = wi / CW;
  } else {
    int tb = bid - nchx * per;
    int tw = nx - nchx * CW;
    bx = nchx * CW + (tb % tw);
    by = tb / tw;
  }
}

// ---------------- pipelined fp16 GEMM: 256x256 tile, BK=32, 3-buffer, single barrier/K-tile ----------------
// 8 waves (2x4), wave tile 128x64: 12 frag-reads per 32 MFMAs (42.7 FLOP/LDS-byte).
// Loop {vmcnt; barrier; stage(t+2); compute(t)}. Write-safety: stage(t+2) writes
// buf (t+2)%3 == (t-1)%3 whose last reader compute(t-1) finished before barrier(t).
// Ledger: 4 gld16/thread/stage; entering iter t outstanding {t,t+1}=8 -> vmcnt(4)
// retires tile t; tail vmcnt(0). Rows are 32 f16 (64B); swizzle slot = kg ^ ((row>>1)&3)
// -> 16 lanes hit 8 distinct 16B positions per 128B window (2-way = free), source
// pre-swizzled so gld16 dest stays linear.
// MODE 0: C(f16) (+f32 dt side-copy for cols >= DTOFF); split-K via blockIdx.z.
// MODE 1: C(f32) + bias (lm-head).
template <int MODE>
__global__ __launch_bounds__(512, 2) void gemm_p3(
    const f16* __restrict__ A, const f16* __restrict__ B,
    f16* __restrict__ Cg, float* __restrict__ Cf,
    float* __restrict__ dtr, const float* __restrict__ bias,
    int N, int Ksub, int lda, int ldb, int ldc)
{
  extern __shared__ char smem[];
  const int tid  = threadIdx.x;
  const int lane = tid & 63;
  const int wid  = tid >> 6;
  int bx, by; swz_tiles(bx, by);
  const int m0 = by * 256;
  const int n0 = bx * 256;
  const size_t kbase = (size_t)blockIdx.z * Ksub;
  if (gridDim.z > 1) Cg += (size_t)blockIdx.z * (size_t)gridDim.y * 256 * ldc;
  const int NT = Ksub >> 5;

  int arA[2], acA[2], brB[2], bcB[2];
#pragma unroll
  for (int L = 0; L < 2; ++L) {
    int q = L * 512 + tid;
    int rl = q >> 2;
    arA[L] = m0 + rl;
    acA[L] = ((q & 3) ^ ((rl >> 1) & 3)) << 3;   // f16 units
    int r = n0 + rl; if (r > N - 1) r = N - 1;
    brB[L] = r;
    bcB[L] = acA[L];
  }

  auto stage = [&](int tt) {
    const int b = tt - (tt / 3) * 3;
    char* Ad = smem + b * 16384;
    char* Bd = smem + 49152 + b * 16384;
    const int kb = tt << 5;
#pragma unroll
    for (int L = 0; L < 2; ++L)
      gld16(A + (size_t)arA[L] * lda + kbase + kb + acA[L], Ad + (L * 512 + tid) * 16);
#pragma unroll
    for (int L = 0; L < 2; ++L)
      gld16(B + (size_t)brB[L] * ldb + kbase + kb + bcB[L], Bd + (L * 512 + tid) * 16);
  };

  const int wm = (wid >> 2) << 7;   // 0,128
  const int wn = (wid & 3) << 6;    // 0,64,128,192
  const int fr = lane & 15;
  const int kg = lane >> 4;

  f32x4 acc[4][8] = {};             // [i col-frag][j row-frag]

  stage(0);
  stage(1);

  for (int t = 0; t < NT; ++t) {
    const int b = t - (t / 3) * 3;
    if (t + 1 < NT) {
      asm volatile("s_waitcnt vmcnt(4)" ::: "memory");
    } else {
      asm volatile("s_waitcnt vmcnt(0)" ::: "memory");
    }
    __builtin_amdgcn_s_barrier();
    asm volatile("" ::: "memory");
    if (t + 2 < NT) stage(t + 2);
    const f16* Ab = (const f16*)(smem + b * 16384);
    const f16* Bb = (const f16*)(smem + 49152 + b * 16384);
    f16x8 af[8], bf[4];
#pragma unroll
    for (int j = 0; j < 8; ++j) {
      int rl = wm + j * 16 + fr;
      af[j] = *(const f16x8*)&Ab[rl * 32 + ((kg ^ ((rl >> 1) & 3)) << 3)];
    }
#pragma unroll
    for (int i = 0; i < 4; ++i) {
      int rl = wn + i * 16 + fr;
      bf[i] = *(const f16x8*)&Bb[rl * 32 + ((kg ^ ((rl >> 1) & 3)) << 3)];
    }
    __builtin_amdgcn_s_setprio(1);
#pragma unroll
    for (int i = 0; i < 4; ++i)
#pragma unroll
      for (int j = 0; j < 8; ++j)
        acc[i][j] = __builtin_amdgcn_mfma_f32_16x16x32_f16(bf[i], af[j], acc[i][j], 0, 0, 0);
    __builtin_amdgcn_s_setprio(0);
    asm volatile("" ::: "memory");
  }

  const int c4 = kg << 2;
#pragma unroll
  for (int i = 0; i < 4; ++i) {
    const int col = n0 + wn + i * 16 + c4;
    if (col >= N) continue;            // N%16==0 -> uniform per frag
#pragma unroll
    for (int j = 0; j < 8; ++j) {
      const int row = m0 + wm + j * 16 + fr;
      if constexpr (MODE == 1) {
        f32x4 bv = bias ? *(const f32x4*)(bias + col) : f32x4{0, 0, 0, 0};
        *(f32x4*)(Cf + (size_t)row * ldc + col) = acc[i][j] + bv;
      } else {
        f16x4 h;
#pragma unroll
        for (int r = 0; r < 4; ++r) h[r] = (f16)acc[i][j][r];
        *(f16x4*)(Cg + (size_t)row * ldc + col) = h;
        if (dtr && col >= DTOFF)
          *(f32x4*)(dtr + (size_t)row * NH + (col - DTOFF)) = acc[i][j];
      }
    }
  }
}

// ---------------- pipelined UV GEMM: G(f16) = (A Bu^T) .* (A Bv^T), 256x128 tile, 2-buffer ----------------
__global__ __launch_bounds__(512, 2) void gemm_uv2(
    const f16* __restrict__ A, const f16* __restrict__ Bu, const f16* __restrict__ Bv,
    f16* __restrict__ Gh)
{
  extern __shared__ char smem[];
  const int tid  = threadIdx.x;
  const int lane = tid & 63;
  const int wid  = tid >> 6;
  int bx, by; swz_tiles(bx, by);
  const int m0 = by * 256;
  const int n0 = bx * 128;
  const int NT = DIM >> 6;

  int arA[4], acA[4];
  const f16* bp[4];
  int bcB[4];
#pragma unroll
  for (int L = 0; L < 4; ++L) {
    int q = L * 512 + tid;
    int row = q >> 3;
    arA[L] = m0 + row;
    acA[L] = ((q & 7) ^ (row & 7)) << 3;
    bcB[L] = acA[L];
    bp[L] = (row < 128) ? (Bu + (size_t)(n0 + row) * DIM)
                        : (Bv + (size_t)(n0 + row - 128) * DIM);
  }

  auto stage = [&](int tt) {
    const int b = tt & 1;
    char* Ad = smem + b * 65536;
    char* Bd = Ad + 32768;
    const int kb = tt << 6;
#pragma unroll
    for (int L = 0; L < 4; ++L)
      gld16(A + (size_t)arA[L] * DIM + kb + acA[L], Ad + (L * 512 + tid) * 16);
#pragma unroll
    for (int L = 0; L < 4; ++L)
      gld16(bp[L] + kb + bcB[L], Bd + (L * 512 + tid) * 16);
  };

  const int wm = (wid >> 1) << 6;
  const int wn = (wid & 1) << 6;
  const int fr = lane & 15;
  const int kg = lane >> 4;

  f32x4 accu[4][4] = {}, accv[4][4] = {};

  stage(0);

  for (int t = 0; t < NT; ++t) {
    if (t + 1 < NT) {
      stage(t + 1);
      asm volatile("s_waitcnt vmcnt(8)" ::: "memory");
    } else {
      asm volatile("s_waitcnt vmcnt(0)" ::: "memory");
    }
    __builtin_amdgcn_s_barrier();
    asm volatile("" ::: "memory");
    const f16* Ab = (const f16*)(smem + (t & 1) * 65536);
    const f16* Bb = Ab + 16384;
#pragma unroll
    for (int s = 0; s < 2; ++s) {
      const int g = kg + s * 4;
      f16x8 af[4], bfu[4], bfv[4];
#pragma unroll
      for (int j = 0; j < 4; ++j) {
        int row = wm + j * 16 + fr;
        af[j] = *(const f16x8*)&Ab[row * 64 + ((g ^ (row & 7)) << 3)];
      }
#pragma unroll
      for (int i = 0; i < 4; ++i) {
        int ru = wn + i * 16 + fr;
        int rv = 128 + wn + i * 16 + fr;
        bfu[i] = *(const f16x8*)&Bb[ru * 64 + ((g ^ (ru & 7)) << 3)];
        bfv[i] = *(const f16x8*)&Bb[rv * 64 + ((g ^ (rv & 7)) << 3)];
      }
      __builtin_amdgcn_s_setprio(1);
#pragma unroll
      for (int i = 0; i < 4; ++i)
#pragma unroll
        for (int j = 0; j < 4; ++j) {
          accu[i][j] = __builtin_amdgcn_mfma_f32_16x16x32_f16(bfu[i], af[j], accu[i][j], 0, 0, 0);
          accv[i][j] = __builtin_amdgcn_mfma_f32_16x16x32_f16(bfv[i], af[j], accv[i][j], 0, 0, 0);
        }
      __builtin_amdgcn_s_setprio(0);
    }
    asm volatile("" ::: "memory");
    __builtin_amdgcn_s_barrier();
    asm volatile("" ::: "memory");
  }

  const int c4 = kg << 2;
#pragma unroll
  for (int i = 0; i < 4; ++i) {
    const int col = n0 + wn + i * 16 + c4;
#pragma unroll
    for (int j = 0; j < 4; ++j) {
      const int row = m0 + wm + j * 16 + fr;
      f16x4 h;
#pragma unroll
      for (int r = 0; r < 4; ++r)
        h[r] = (f16)(accu[i][j][r] * accv[i][j][r]);
      *(f16x4*)(Gh + (size_t)row * FFN + col) = h;
    }
  }
}

// fused split-K reduce + rms (parts f16)
template <bool DORMS>
__global__ __launch_bounds__(256) void reduce_rms(const f16* __restrict__ parts,
                                                  const float* __restrict__ resid,
                                                  float* __restrict__ xn,
                                                  f16* __restrict__ outh, int np)
{
  const int row = blockIdx.x, tid = threadIdx.x;
  const size_t base = (size_t)row * DIM + tid * 4;
  f32x4 s = *(const f32x4*)(resid + base);
  for (int p = 0; p < np; ++p) {
    f16x4 pv = *(const f16x4*)(parts + (size_t)p * (NTOK * DIM) + base);
#pragma unroll
    for (int c = 0; c < 4; ++c) s[c] += (float)pv[c];
  }
  if constexpr (!DORMS) {
    f16x4 h;
#pragma unroll
    for (int c = 0; c < 4; ++c) h[c] = (f16)s[c];
    *(f16x4*)(outh + base) = h;
    return;
  }
  float ss = s[0] * s[0] + s[1] * s[1] + s[2] * s[2] + s[3] * s[3];
  for (int o = 32; o; o >>= 1) ss += __shfl_down(ss, o);
  __shared__ float red[4];
  if ((tid & 63) == 0) red[tid >> 6] = ss;
  __syncthreads();
  ss = red[0] + red[1] + red[2] + red[3];
  const float sc = rsqrtf(ss * (1.f / 1024.f) + 1e-6f);
  f32x4 o4 = s * sc;
  *(f32x4*)(xn + base) = o4;
  f16x4 h;
#pragma unroll
  for (int c = 0; c < 4; ++c) h[c] = (f16)o4[c];
  *(f16x4*)(outh + base) = h;
}

// ---------------- small kernels ----------------
__global__ __launch_bounds__(256) void cvt_f2h_k(const float* __restrict__ src,
                                                 f16* __restrict__ dst, int n)
{
  for (size_t i = ((size_t)blockIdx.x * 256 + threadIdx.x) * 4; i < (size_t)n;
       i += (size_t)gridDim.x * 1024) {
    f32x4 v = *(const f32x4*)(src + i);
    f16x4 o;
#pragma unroll
    for (int c = 0; c < 4; ++c) o[c] = (f16)v[c];
    *(f16x4*)(dst + i) = o;
  }
}

// all-layer weight conversion (one dispatch, 74880 blocks)
__global__ __launch_bounds__(256) void cvt_wts(
    const float* __restrict__ inw, const float* __restrict__ outw,
    const float* __restrict__ uw, const float* __restrict__ vw,
    const float* __restrict__ ow,
    f16* __restrict__ w_in, f16* __restrict__ w_out,
    f16* __restrict__ w_uv, f16* __restrict__ w_o)
{
  const int b = blockIdx.x;
  const float* src; f16* dst;
  if (b < 17536) {
    int li = b / 4384, ib = b - li * 4384;
    src = inw  + (size_t)li * 4489216 + (size_t)ib * 1024;
    dst = w_in + (size_t)li * 4489216 + (size_t)ib * 1024;
  } else if (b < 25728) {
    int lb = b - 17536, li = lb >> 11, ib = lb & 2047;
    src = outw  + (size_t)li * 2097152 + (size_t)ib * 1024;
    dst = w_out + (size_t)li * 2097152 + (size_t)ib * 1024;
  } else if (b < 42112) {
    int lb = b - 25728, li = lb >> 12, ib = lb & 4095;
    src = uw   + (size_t)li * 4194304 + (size_t)ib * 1024;
    dst = w_uv + (size_t)li * 8388608 + (size_t)ib * 1024;
  } else if (b < 58496) {
    int lb = b - 42112, li = lb >> 12, ib = lb & 4095;
    src = vw   + (size_t)li * 4194304 + (size_t)ib * 1024;
    dst = w_uv + (size_t)li * 8388608 + 4194304 + (size_t)ib * 1024;
  } else {
    int lb = b - 58496, li = lb >> 12, ib = lb & 4095;
    src = ow  + (size_t)li * 4194304 + (size_t)ib * 1024;
    dst = w_o + (size_t)li * 4194304 + (size_t)ib * 1024;
  }
  const size_t i = (size_t)threadIdx.x * 4;
  f32x4 v = *(const f32x4*)(src + i);
  f16x4 o;
#pragma unroll
  for (int c = 0; c < 4; ++c) o[c] = (f16)v[c];
  *(f16x4*)(dst + i) = o;
}

__global__ __launch_bounds__(256) void gather_k(const int* __restrict__ tok,
                                                const float* __restrict__ emb,
                                                float* __restrict__ x)
{
  const int row = blockIdx.x;
  const int t = tok[row];
  const f32x4* s = (const f32x4*)(emb + (size_t)t * DIM);
  f32x4* d = (f32x4*)(x + (size_t)row * DIM);
  d[threadIdx.x] = s[threadIdx.x];
}

__global__ __launch_bounds__(256) void rms1024(const float* __restrict__ in,
                                               float* __restrict__ outf,
                                               f16* __restrict__ outh)
{
  const int row = blockIdx.x, tid = threadIdx.x;
  f32x4 v = ((const f32x4*)(in + (size_t)row * DIM))[tid];
  float ss = v[0] * v[0] + v[1] * v[1] + v[2] * v[2] + v[3] * v[3];
  for (int o = 32; o; o >>= 1) ss += __shfl_down(ss, o);
  __shared__ float red[4];
  if ((tid & 63) == 0) red[tid >> 6] = ss;
  __syncthreads();
  ss = red[0] + red[1] + red[2] + red[3];
  const float sc = rsqrtf(ss * (1.f / 1024.f) + 1e-6f);
  f32x4 o4 = v * sc;
  ((f32x4*)(outf + (size_t)row * DIM))[tid] = o4;
  f16x4 h;
#pragma unroll
  for (int c = 0; c < 4; ++c) h[c] = (f16)o4[c];
  ((f16x4*)(outh + (size_t)row * DIM))[tid] = h;
}

// merged conv+silu (f16 in/out) / dt+ca (f32 dtraw side-buffer)
__global__ __launch_bounds__(256) void convdt(const f16* __restrict__ zx,
                                              const float* __restrict__ dtrw,
                                              const float* __restrict__ cw,
                                              const float* __restrict__ cbias,
                                              const float* __restrict__ dtb,
                                              const float* __restrict__ alog,
                                              f16* __restrict__ xbc,
                                              float* __restrict__ dt,
                                              float* __restrict__ ca)
{
  if (blockIdx.x < 576) {
    const int sid = blockIdx.x * 256 + threadIdx.x;
    const int c0 = (sid % 576) * 4;
    const int t0 = (sid / 576) * 16;
    float w[4][4], bs[4];
#pragma unroll
    for (int cc = 0; cc < 4; ++cc) {
      f32x4 wv = *(const f32x4*)(cw + (size_t)(c0 + cc) * 4);
      w[cc][0] = wv[0]; w[cc][1] = wv[1]; w[cc][2] = wv[2]; w[cc][3] = wv[3];
      bs[cc] = cbias[c0 + cc];
    }
    const int l0 = t0 & (LSEQ - 1);
    float x3[4] = {}, x2[4] = {}, x1[4] = {};
    if (l0 != 0) {
      f16x4 a = *(const f16x4*)(zx + (size_t)(t0 - 3) * DPROJ + DIN + c0);
      f16x4 b = *(const f16x4*)(zx + (size_t)(t0 - 2) * DPROJ + DIN + c0);
      f16x4 d = *(const f16x4*)(zx + (size_t)(t0 - 1) * DPROJ + DIN + c0);
#pragma unroll
      for (int c = 0; c < 4; ++c) { x3[c] = (float)a[c]; x2[c] = (float)b[c]; x1[c] = (float)d[c]; }
    }
    for (int i = 0; i < 16; ++i) {
      const int t = t0 + i;
      f16x4 xcv = *(const f16x4*)(zx + (size_t)t * DPROJ + DIN + c0);
      f16x4 o;
#pragma unroll
      for (int cc = 0; cc < 4; ++cc) {
        float xc = (float)xcv[cc];
        float a = bs[cc] + x3[cc] * w[cc][0] + x2[cc] * w[cc][1] +
                  x1[cc] * w[cc][2] + xc * w[cc][3];
        o[cc] = (f16)(a / (1.f + expf(-a)));
        x3[cc] = x2[cc]; x2[cc] = x1[cc]; x1[cc] = xc;
      }
      *(f16x4*)(xbc + (size_t)t * CONVDIM + c0) = o;
    }
  } else {
    const int loc = (threadIdx.x >> 7) * 128;
    const int u = (blockIdx.x - 576) * 2 + (threadIdx.x >> 7);
    const int bc = u >> 5, h = u & 31, q = threadIdx.x & 127;
    const int t = bc * 128 + q;
    float raw = dtrw[(size_t)t * NH + h] + dtb[h];
    float d = raw > 20.f ? raw : log1pf(expf(raw));
    dt[t * 32 + h] = d;
    float a = -expf(alog[h]) * d;
    __shared__ float s[256];
    s[loc + q] = a;
    __syncthreads();
    for (int off = 1; off < 128; off <<= 1) {
      float v = (q >= off) ? s[loc + q - off] : 0.f;
      __syncthreads();
      s[loc + q] += v;
      __syncthreads();
    }
    ca[(size_t)u * 128 + q] = s[loc + q];
  }
}

// MFMA CB: CB[i][j] = sum_n C[i,n]*B[j,n]
__global__ __launch_bounds__(256) void cb_mfma(const f16* __restrict__ xbc,
                                               float* __restrict__ CBo)
{
  const int bc = blockIdx.x;
  __shared__ f16 Cm[128 * 72], Bm[128 * 72];
  const int tid = threadIdx.x, lane = tid & 63, wid = tid >> 6;
  const int fr = lane & 15, kg = lane >> 4;
  f32x4 acc[2][8] = {};
  const int i = tid & 127;
  const f16* rowp = xbc + (size_t)(bc * 128 + i) * CONVDIM + DIN;

  for (int kh = 0; kh < 2; ++kh) {
#pragma unroll
    for (int it = 0; it < 8; ++it) {
      int idx = it * 256 + tid;
      int n0 = (idx >> 7) * 4;
      *(f16x4*)&Bm[i * 72 + n0] = *(const f16x4*)(rowp + kh * 64 + n0);
      *(f16x4*)&Cm[i * 72 + n0] = *(const f16x4*)(rowp + DSTATE + kh * 64 + n0);
    }
    __syncthreads();
#pragma unroll
    for (int kf = 0; kf < 2; ++kf) {
      const int ko = kf * 32 + kg * 8;
      f16x8 cf[2], bf[8];
#pragma unroll
      for (int ii = 0; ii < 2; ++ii)
        cf[ii] = *(const f16x8*)&Cm[((wid * 2 + ii) * 16 + fr) * 72 + ko];
#pragma unroll
      for (int jj = 0; jj < 8; ++jj)
        bf[jj] = *(const f16x8*)&Bm[(jj * 16 + fr) * 72 + ko];
      __builtin_amdgcn_s_setprio(1);
#pragma unroll
      for (int ii = 0; ii < 2; ++ii)
#pragma unroll
        for (int jj = 0; jj < 8; ++jj)
          acc[ii][jj] = __builtin_amdgcn_mfma_f32_16x16x32_f16(cf[ii], bf[jj], acc[ii][jj], 0, 0, 0);
      __builtin_amdgcn_s_setprio(0);
    }
    __syncthreads();
  }
  float* out = CBo + (size_t)bc * 16384;
#pragma unroll
  for (int ii = 0; ii < 2; ++ii) {
    const int i0 = (wid * 2 + ii) * 16 + kg * 4;
#pragma unroll
    for (int jj = 0; jj < 8; ++jj) {
      const int j = jj * 16 + fr;
#pragma unroll
      for (int r = 0; r < 4; ++r)
        out[(size_t)(i0 + r) * 128 + j] = acc[ii][jj][r];
    }
  }
}

// MFMA states: ST[p][n] = sum_j w_j*B[j][n]*x[j][p]
__global__ __launch_bounds__(256) void ssd_states(const f16* __restrict__ xbc,
                                                  const float* __restrict__ dt,
                                                  const float* __restrict__ ca,
                                                  float* __restrict__ ST)
{
  const int bc = blockIdx.x >> 5, h = blockIdx.x & 31;
  __shared__ f16 Am[128 * 136];
  __shared__ f16 Bm[64 * 136];
  __shared__ float warr[128];
  const int tid = threadIdx.x, lane = tid & 63, wid = tid >> 6;
  if (tid < 128) {
    float cv = ca[(size_t)blockIdx.x * 128 + tid];
    float cl = ca[(size_t)blockIdx.x * 128 + 127];
    warr[tid] = expf(cl - cv) * dt[(size_t)(bc * 128 + tid) * 32 + h];
  }
  __syncthreads();
  {
    const int j = tid & 127;
    const float wj = warr[j];
    const f16* br = xbc + (size_t)(bc * 128 + j) * CONVDIM + DIN;
#pragma unroll
    for (int it = 0; it < 16; ++it) {
      int idx = it * 256 + tid;
      int n0 = (idx >> 7) * 4;
      f16x4 v = *(const f16x4*)(br + n0);
#pragma unroll
      for (int c = 0; c < 4; ++c) Am[(n0 + c) * 136 + j] = (f16)((float)v[c] * wj);
    }
    const f16* xr = xbc + (size_t)(bc * 128 + j) * CONVDIM + h * 64;
#pragma unroll
    for (int it = 0; it < 8; ++it) {
      int idx = it * 256 + tid;
      int p0 = (idx >> 7) * 4;
      f16x4 v = *(const f16x4*)(xr + p0);
#pragma unroll
      for (int c = 0; c < 4; ++c) Bm[(p0 + c) * 136 + j] = v[c];
    }
  }
  __syncthreads();
  const int fr = lane & 15, kg = lane >> 4;
  f32x4 acc[2][4] = {};
#pragma unroll
  for (int kf = 0; kf < 4; ++kf) {
    const int ko = kf * 32 + kg * 8;
    f16x8 bw[2], xf[4];
#pragma unroll
    for (int ii = 0; ii < 2; ++ii)
      bw[ii] = *(const f16x8*)&Am[((wid * 2 + ii) * 16 + fr) * 136 + ko];
#pragma unroll
    for (int pi = 0; pi < 4; ++pi)
      xf[pi] = *(const f16x8*)&Bm[(pi * 16 + fr) * 136 + ko];
    __builtin_amdgcn_s_setprio(1);
#pragma unroll
    for (int ii = 0; ii < 2; ++ii)
#pragma unroll
      for (int pi = 0; pi < 4; ++pi)
        acc[ii][pi] = __builtin_amdgcn_mfma_f32_16x16x32_f16(bw[ii], xf[pi], acc[ii][pi], 0, 0, 0);
    __builtin_amdgcn_s_setprio(0);
  }
  float* sb = ST + (size_t)blockIdx.x * 8192;
#pragma unroll
  for (int ii = 0; ii < 2; ++ii) {
    const int n0 = (wid * 2 + ii) * 16 + kg * 4;
#pragma unroll
    for (int pi = 0; pi < 4; ++pi) {
      const int p = pi * 16 + fr;
      *(f32x4*)(sb + (size_t)p * 128 + n0) = acc[ii][pi];
    }
  }
}

// inter-chunk scan (f32 states)
__global__ __launch_bounds__(256) void scan_k(const float* __restrict__ ca,
                                              float* __restrict__ states)
{
  const int b = blockIdx.x >> 10, h = (blockIdx.x >> 5) & 31, seg = blockIdx.x & 31;
  const int e = seg * 256 + threadIdx.x;
  float s = 0.f;
  for (int c = 0; c < CPB; ++c) {
    int bc = b * CPB + c;
    float cd = expf(ca[(size_t)(bc * 32 + h) * 128 + 127]);
    size_t idx = (size_t)(bc * 32 + h) * 8192 + e;
    float v = states[idx];
    states[idx] = s;
    s = s * cd + v;
  }
}

// MFMA fused y = T@XD + exp(ca)*(C@ST^T) + D*x
__global__ __launch_bounds__(256) void ssd_y(const f16* __restrict__ xbc,
                                             const float* __restrict__ dt,
                                             const float* __restrict__ ca,
                                             const float* __restrict__ CB,
                                             const float* __restrict__ Dvec,
                                             const float* __restrict__ ST,
                                             f16* __restrict__ ybuf)
{
  const int bc = blockIdx.x >> 5, h = blockIdx.x & 31;
  __shared__ f16 Am[128 * 136];
  __shared__ f16 Bm[64 * 136];
  __shared__ float cas[128], dtl[128];
  const int tid = threadIdx.x, lane = tid & 63, wid = tid >> 6;
  if (tid < 128) {
    cas[tid] = ca[(size_t)blockIdx.x * 128 + tid];
    dtl[tid] = dt[(size_t)(bc * 128 + tid) * 32 + h];
  }
  __syncthreads();
  {
    const int j = tid & 127;
    const float dj = dtl[j];
    const f16* xr = xbc + (size_t)(bc * 128 + j) * CONVDIM + h * 64;
#pragma unroll
    for (int it = 0; it < 8; ++it) {
      int idx = it * 256 + tid;
      int p0 = (idx >> 7) * 4;
      f16x4 v = *(const f16x4*)(xr + p0);
#pragma unroll
      for (int c = 0; c < 4; ++c) Bm[(p0 + c) * 136 + j] = (f16)((float)v[c] * dj);
    }
  }
  {
    const int i = tid >> 1;
    const int jh = (tid & 1) * 64;
    const float cai = cas[i];
    const float* cbr = CB + (size_t)bc * 16384 + (size_t)i * 128 + jh;
#pragma unroll
    for (int g = 0; g < 8; ++g) {
      int j0 = g * 8;
      f32x4 v0 = *(const f32x4*)(cbr + j0);
      f32x4 v1 = *(const f32x4*)(cbr + j0 + 4);
      f16x8 tv;
#pragma unroll
      for (int c = 0; c < 8; ++c) {
        int j = jh + j0 + c;
        float cbv = (c < 4) ? v0[c] : v1[c - 4];
        float val = (j <= i) ? cbv * expf(cai - cas[j]) : 0.f;
        tv[c] = (f16)val;
      }
      *(f16x8*)&Am[i * 136 + jh + j0] = tv;
    }
  }
  __syncthreads();
  const int fr = lane & 15, kg = lane >> 4;
  f32x4 a1[2][4] = {}, a2[2][4] = {};
#pragma unroll
  for (int kf = 0; kf < 4; ++kf) {
    const int ko = kf * 32 + kg * 8;
    f16x8 xf[4], tf[2];
#pragma unroll
    for (int pi = 0; pi < 4; ++pi)
      xf[pi] = *(const f16x8*)&Bm[(pi * 16 + fr) * 136 + ko];
#pragma unroll
    for (int ii = 0; ii < 2; ++ii)
      tf[ii] = *(const f16x8*)&Am[((wid * 2 + ii) * 16 + fr) * 136 + ko];
    __builtin_amdgcn_s_setprio(1);
#pragma unroll
    for (int ii = 0; ii < 2; ++ii)
#pragma unroll
      for (int pi = 0; pi < 4; ++pi)
        a1[ii][pi] = __builtin_amdgcn_mfma_f32_16x16x32_f16(xf[pi], tf[ii], a1[ii][pi], 0, 0, 0);
    __builtin_amdgcn_s_setprio(0);
  }
  __syncthreads();
  {
    const int i = tid & 127;
    const f16* cr = xbc + (size_t)(bc * 128 + i) * CONVDIM + DIN + DSTATE;
#pragma unroll
    for (int it = 0; it < 16; ++it) {
      int idx = it * 256 + tid;
      int n0 = (idx >> 7) * 4;
      *(f16x4*)&Am[i * 136 + n0] = *(const f16x4*)(cr + n0);
    }
    const float* sr = ST + (size_t)blockIdx.x * 8192;
    const int p = tid & 63;
#pragma unroll
    for (int it = 0; it < 8; ++it) {
      int idx = it * 256 + tid;
      int n0 = (idx >> 6) * 4;
      f32x4 v = *(const f32x4*)(sr + (size_t)p * 128 + n0);
      f16x4 hv;
#pragma unroll
      for (int c = 0; c < 4; ++c) hv[c] = (f16)v[c];
      *(f16x4*)&Bm[p * 136 + n0] = hv;
    }
  }
  __syncthreads();
#pragma unroll
  for (int kf = 0; kf < 4; ++kf) {
    const int ko = kf * 32 + kg * 8;
    f16x8 sf[4], cf[2];
#pragma unroll
    for (int pi = 0; pi < 4; ++pi)
      sf[pi] = *(const f16x8*)&Bm[(pi * 16 + fr) * 136 + ko];
#pragma unroll
    for (int ii = 0; ii < 2; ++ii)
      cf[ii] = *(const f16x8*)&Am[((wid * 2 + ii) * 16 + fr) * 136 + ko];
    __builtin_amdgcn_s_setprio(1);
#pragma unroll
    for (int ii = 0; ii < 2; ++ii)
#pragma unroll
      for (int pi = 0; pi < 4; ++pi)
        a2[ii][pi] = __builtin_amdgcn_mfma_f32_16x16x32_f16(sf[pi], cf[ii], a2[ii][pi], 0, 0, 0);
    __builtin_amdgcn_s_setprio(0);
  }
  const float dh = Dvec[h];
#pragma unroll
  for (int ii = 0; ii < 2; ++ii) {
    const int i = (wid * 2 + ii) * 16 + fr;
    const float ei = expf(cas[i]);
    const int tg = bc * 128 + i;
#pragma unroll
    for (int pi = 0; pi < 4; ++pi) {
      const int p0 = pi * 16 + kg * 4;
      f16x4 xv = *(const f16x4*)(xbc + (size_t)tg * CONVDIM + h * 64 + p0);
      f16x4 yo;
#pragma unroll
      for (int r = 0; r < 4; ++r)
        yo[r] = (f16)(a1[ii][pi][r] + ei * a2[ii][pi][r] + dh * (float)xv[r]);
      *(f16x4*)(ybuf + (size_t)tg * DIN + h * 64 + p0) = yo;
    }
  }
}

// yg = y*silu(z); rms(2048) * mnorm_w -> fp16
__global__ __launch_bounds__(256) void gate_rms(const f16* __restrict__ ybuf,
                                                const f16* __restrict__ zx,
                                                const float* __restrict__ nw,
                                                f16* __restrict__ outh)
{
  const int row = blockIdx.x, tid = threadIdx.x;
  f16x8 yv = *(const f16x8*)(ybuf + (size_t)row * DIN + tid * 8);
  f16x8 zv = *(const f16x8*)(zx + (size_t)row * DPROJ + tid * 8);
  float g[8];
  float ss = 0.f;
#pragma unroll
  for (int c = 0; c < 8; ++c) {
    float z = (float)zv[c];
    g[c] = (float)yv[c] * (z / (1.f + expf(-z)));
    ss += g[c] * g[c];
  }
  for (int o = 32; o; o >>= 1) ss += __shfl_down(ss, o);
  __shared__ float red[4];
  if ((tid & 63) == 0) red[tid >> 6] = ss;
  __syncthreads();
  ss = red[0] + red[1] + red[2] + red[3];
  const float sc = rsqrtf(ss * (1.f / 2048.f) + 1e-6f);
  f32x4 w0 = *(const f32x4*)(nw + tid * 8);
  f32x4 w1 = *(const f32x4*)(nw + tid * 8 + 4);
  f16x8 h;
#pragma unroll
  for (int c = 0; c < 8; ++c) {
    float w = (c < 4) ? w0[c] : w1[c - 4];
    h[c] = (f16)(g[c] * sc * w);
  }
  *(f16x8*)(outh + (size_t)row * DIN + tid * 8) = h;
}

// ---------------- launcher ----------------
extern "C" void kernel_launch(void* const* d_in, const int* in_sizes, int n_in,
                              void* d_out, int out_size, void* d_ws, size_t ws_size,
                              hipStream_t stream)
{
  (void)in_sizes; (void)n_in; (void)out_size; (void)ws_size;
  const int*   tokens = (const int*)d_in[0];
  const float* emb    = (const float*)d_in[1];
  const float* lmb    = (const float*)d_in[2];
  const float* inw    = (const float*)d_in[3];
  const float* cw     = (const float*)d_in[4];
  const float* cbias  = (const float*)d_in[5];
  const float* dtb    = (const float*)d_in[6];
  const float* alog   = (const float*)d_in[7];
  const float* Dvec   = (const float*)d_in[8];
  const float* nw     = (const float*)d_in[9];
  const float* outw   = (const float*)d_in[10];
  const float* uw     = (const float*)d_in[11];
  const float* vw     = (const float*)d_in[12];
  const float* ow     = (const float*)d_in[13];

  char* ws = (char*)d_ws;
  size_t off = 0;
  auto alloc = [&](size_t bytes) { void* p = ws + off; off += (bytes + 255) & ~(size_t)255; return p; };
  f16* emb_h   = (f16*)alloc((size_t)VOCAB * DIM * 2);
  float* xbuf  = (float*)alloc((size_t)NTOK * DIM * 4);
  float* xn    = (float*)alloc((size_t)NTOK * DIM * 4);
  f16* xnh     = (f16*)alloc((size_t)NTOK * DIM * 2);
  f16* xh_lm   = (f16*)alloc((size_t)NTOK * DIM * 2);
  float* dtraw = (float*)alloc((size_t)NTOK * NH * 4);
  float* dtbuf = (float*)alloc((size_t)NTOK * NH * 4);
  float* cabuf = (float*)alloc((size_t)NCHUNK * NH * QLEN * 4);
  float* CBbuf = (float*)alloc((size_t)NCHUNK * QLEN * QLEN * 4);
  f16* abh     = (f16*)alloc((size_t)NTOK * FFN * 2);

  // d_out transients + converted weights (all overwritten by final lm-head GEMM)
  char* ob = (char*)d_out;
  float* states = (float*)(ob);
  f16* zxb      = (f16*)(ob + 40000000);
  f16* xbc      = (f16*)(ob + 80000000);
  f16* ybuf     = (f16*)(ob + 100000000);
  f16* parts    = (f16*)(ob + 120000000);            // 4 x 8.4 MB
  f16* w_in     = (f16*)(ob + 160000000);
  f16* w_out    = (f16*)(ob + 196000000);
  f16* w_uv     = (f16*)(ob + 213000000);
  f16* w_o      = (f16*)(ob + 281000000);

  cvt_f2h_k<<<4096, 256, 0, stream>>>(emb, emb_h, VOCAB * DIM);
  cvt_wts<<<74880, 256, 0, stream>>>(inw, outw, uw, vw, ow, w_in, w_out, w_uv, w_o);
  gather_k<<<NTOK, 256, 0, stream>>>(tokens, emb, xbuf);
  rms1024<<<NTOK, 256, 0, stream>>>(xbuf, xn, xnh);

  for (int it = 0; it < 2 * NLAYER; ++it) {
    const int li = it >> 1;
    const f16* w_inL  = w_in  + (size_t)li * 4489216;
    const f16* w_outL = w_out + (size_t)li * 2097152;
    const f16* w_uL   = w_uv  + (size_t)li * 8388608;
    const f16* w_vL   = w_uL  + 4194304;
    const f16* w_oL   = w_o   + (size_t)li * 4194304;
    // mamba
    gemm_p3<0><<<dim3((DPROJ + 255) / 256, NTOK / 256, 1), 512, SMEM3, stream>>>(
        xnh, w_inL, zxb, nullptr, dtraw, nullptr, DPROJ, DIM, DIM, DIM, DPROJ);
    convdt<<<1088, 256, 0, stream>>>(zxb, dtraw, cw + (size_t)li * CONVDIM * DCONV,
                                     cbias + (size_t)li * CONVDIM,
                                     dtb + li * NH, alog + li * NH, xbc, dtbuf, cabuf);
    cb_mfma<<<NCHUNK, 256, 0, stream>>>(xbc, CBbuf);
    ssd_states<<<NCHUNK * NH, 256, 0, stream>>>(xbc, dtbuf, cabuf, states);
    scan_k<<<2048, 256, 0, stream>>>(cabuf, states);
    ssd_y<<<NCHUNK * NH, 256, 0, stream>>>(xbc, dtbuf, cabuf, CBbuf,
                                           Dvec + li * NH, states, ybuf);
    gate_rms<<<NTOK, 256, 0, stream>>>(ybuf, zxb, nw + (size_t)li * DIN, abh);
    // out_proj: split-K x4 -> f16 parts; fused reduce(+resid) + rms
    gemm_p3<0><<<dim3(DIM / 256, NTOK / 256, 4), 512, SMEM3, stream>>>(
        abh, w_outL, parts, nullptr, nullptr, nullptr, DIM, DIN / 4, DIN, DIN, DIM);
    reduce_rms<true><<<NTOK, 256, 0, stream>>>(parts, xn, xn, xnh, 4);
    // gated FFN
    gemm_uv2<<<dim3(FFN / 128, NTOK / 256, 1), 512, SMEM2, stream>>>(
        xnh, w_uL, w_vL, abh);
    // o_proj: split-K x4
    gemm_p3<0><<<dim3(DIM / 256, NTOK / 256, 4), 512, SMEM3, stream>>>(
        abh, w_oL, parts, nullptr, nullptr, nullptr, DIM, FFN / 4, FFN, FFN, DIM);
    if (it < 2 * NLAYER - 1)
      reduce_rms<true><<<NTOK, 256, 0, stream>>>(parts, xn, xn, xnh, 4);
    else
      reduce_rms<false><<<NTOK, 256, 0, stream>>>(parts, xn, nullptr, xh_lm, 4);
  }

  // lm head (MODE 1: f32 out + bias)
  gemm_p3<1><<<dim3(VOCAB / 256, NTOK / 256, 1), 512, SMEM3, stream>>>(
      xh_lm, emb_h, nullptr, (float*)d_out, nullptr, lmb, VOCAB, DIM, DIM, DIM, VOCAB);
}

// Round 17
// 3039.966 us; speedup vs baseline: 1.0782x; 1.0782x over previous
//
#include <hip/hip_runtime.h>
#include <hip/hip_bf16.h>

// ---------------- problem constants ----------------
#define BSZ 2
#define LSEQ 2048
#define DIM 1024
#define VOCAB 32000
#define NLAYER 4
#define DSTATE 128
#define DCONV 4
#define HEADDIM 64
#define DIN 2048
#define NH 32
#define CONVDIM 2304          // DIN + 2*DSTATE
#define DPROJ 4384            // 2*DIN + 2*DSTATE + NH
#define FFN 4096
#define QLEN 128
#define NTOK 4096             // BSZ*LSEQ
#define NCHUNK 32             // NTOK/QLEN
#define CPB 16                // chunks per batch
#define DTOFF 4352            // DIN + CONVDIM

#define SMEM_BYTES 147456     // gemm_p: 3 x (A 32KB + B 16KB)
#define SMEM2 131072          // gemm_uv2: 2 x (A 32KB + B 32KB)

using f32x4 = __attribute__((ext_vector_type(4))) float;
using f16   = _Float16;
using f16x4 = __attribute__((ext_vector_type(4))) _Float16;
using f16x8 = __attribute__((ext_vector_type(8))) _Float16;

__device__ __forceinline__ void gld16(const void* g, void* l) {
  __builtin_amdgcn_global_load_lds(
      (const __attribute__((address_space(1))) unsigned int*)g,
      (__attribute__((address_space(3))) unsigned int*)l, 16, 0, 0);
}

// Tile swizzle: XCD-contiguous + column-chunked
__device__ __forceinline__ void swz_tiles(int& bx, int& by) {
  const int nx = gridDim.x, ny = gridDim.y;
  const int nwg = nx * ny;
  int bid = blockIdx.y * nx + blockIdx.x;
  if ((nwg & 7) == 0) bid = (bid & 7) * (nwg >> 3) + (bid >> 3);
  const int CW = 8;
  const int nchx = nx / CW;
  const int per = CW * ny;
  const int ch = bid / per;
  if (ch < nchx) {
    int wi = bid - ch * per;
    bx = ch * CW + (wi & (CW - 1));
    by = wi / CW;
  } else {
    int tb = bid - nchx * per;
    int tw = nx - nchx * CW;
    bx = nchx * CW + (tb % tw);
    by = tb / tw;
  }
}

// ---------------- pipelined fp16 GEMM: 256x128 tile, BK=64, 3-buffer, SINGLE barrier/K-tile ----------------
// Loop order {vmcnt; barrier; stage(t+2); compute(t)}. Write-safety: stage(t+2)
// writes buf (t+2)%3 == (t-1)%3 whose last reader (compute(t-1)) finished before
// any wave passed barrier(t). Ledger: 6 gld16/thread/stage; entering iter t the
// outstanding set is {stage(t), stage(t+1)} = 12 -> vmcnt(6) retires tile t;
// tail t==NT-1 -> vmcnt(0). XOR swizzle slot=g^(row&7), pre-swizzled source.
// MODE 0: C(f16) (+optional f32 dt side-copy for cols >= DTOFF); split-K via z.
// MODE 1: C(f32) + bias (lm-head).
template <int MODE>
__global__ __launch_bounds__(512, 2) void gemm_p(
    const f16* __restrict__ A, const f16* __restrict__ B,
    f16* __restrict__ Cg, float* __restrict__ Cf,
    float* __restrict__ dtr, const float* __restrict__ bias,
    int N, int Ksub, int lda, int ldb, int ldc)
{
  extern __shared__ char smem[];
  const int tid  = threadIdx.x;
  const int lane = tid & 63;
  const int wid  = tid >> 6;
  int bx, by; swz_tiles(bx, by);
  const int m0 = by * 256;
  const int n0 = bx * 128;
  const size_t kbase = (size_t)blockIdx.z * Ksub;
  if (gridDim.z > 1) Cg += (size_t)blockIdx.z * (size_t)gridDim.y * 256 * ldc;
  const int NT = Ksub >> 6;

  int arA[4], acA[4];
#pragma unroll
  for (int L = 0; L < 4; ++L) {
    int q = L * 512 + tid;
    int row = q >> 3;
    arA[L] = m0 + row;
    acA[L] = ((q & 7) ^ (row & 7)) << 3;
  }
  int brB[2], bcB[2];
#pragma unroll
  for (int L = 0; L < 2; ++L) {
    int q = L * 512 + tid;
    int row = q >> 3;
    int r = n0 + row; if (r > N - 1) r = N - 1;
    brB[L] = r;
    bcB[L] = ((q & 7) ^ (row & 7)) << 3;
  }

  auto stage = [&](int tt) {
    const int b = tt - (tt / 3) * 3;
    char* Ad = smem + b * 32768;
    char* Bd = smem + 98304 + b * 16384;
    const int kb = tt << 6;
#pragma unroll
    for (int L = 0; L < 4; ++L)
      gld16(A + (size_t)arA[L] * lda + kbase + kb + acA[L], Ad + (L * 512 + tid) * 16);
#pragma unroll
    for (int L = 0; L < 2; ++L)
      gld16(B + (size_t)brB[L] * ldb + kbase + kb + bcB[L], Bd + (L * 512 + tid) * 16);
  };

  const int wm = (wid >> 1) << 6;
  const int wn = (wid & 1) << 6;
  const int fr = lane & 15;
  const int kg = lane >> 4;

  f32x4 acc[4][4] = {};

  stage(0);
  stage(1);

  for (int t = 0; t < NT; ++t) {
    const int b = t - (t / 3) * 3;
    if (t + 1 < NT) {
      asm volatile("s_waitcnt vmcnt(6)" ::: "memory");
    } else {
      asm volatile("s_waitcnt vmcnt(0)" ::: "memory");
    }
    __builtin_amdgcn_s_barrier();
    asm volatile("" ::: "memory");
    if (t + 2 < NT) stage(t + 2);
    const f16* Ab = (const f16*)(smem + b * 32768);
    const f16* Bb = (const f16*)(smem + 98304 + b * 16384);
#pragma unroll
    for (int s = 0; s < 2; ++s) {
      f16x8 af[4], bf[4];
#pragma unroll
      for (int j = 0; j < 4; ++j) {
        int row = wm + j * 16 + fr;
        int g = kg + s * 4;
        af[j] = *(const f16x8*)&Ab[row * 64 + ((g ^ (row & 7)) << 3)];
      }
#pragma unroll
      for (int i = 0; i < 4; ++i) {
        int row = wn + i * 16 + fr;
        int g = kg + s * 4;
        bf[i] = *(const f16x8*)&Bb[row * 64 + ((g ^ (row & 7)) << 3)];
      }
      __builtin_amdgcn_s_setprio(1);
#pragma unroll
      for (int i = 0; i < 4; ++i)
#pragma unroll
        for (int j = 0; j < 4; ++j)
          acc[i][j] = __builtin_amdgcn_mfma_f32_16x16x32_f16(bf[i], af[j], acc[i][j], 0, 0, 0);
      __builtin_amdgcn_s_setprio(0);
    }
    asm volatile("" ::: "memory");
  }

  const int c4 = kg << 2;
#pragma unroll
  for (int i = 0; i < 4; ++i) {
    const int col = n0 + wn + i * 16 + c4;
    if (col >= N) continue;            // N%16==0 -> uniform per frag
#pragma unroll
    for (int j = 0; j < 4; ++j) {
      const int row = m0 + wm + j * 16 + fr;
      if constexpr (MODE == 1) {
        f32x4 bv = bias ? *(const f32x4*)(bias + col) : f32x4{0, 0, 0, 0};
        *(f32x4*)(Cf + (size_t)row * ldc + col) = acc[i][j] + bv;
      } else {
        f16x4 h;
#pragma unroll
        for (int r = 0; r < 4; ++r) h[r] = (f16)acc[i][j][r];
        *(f16x4*)(Cg + (size_t)row * ldc + col) = h;
        if (dtr && col >= DTOFF)
          *(f32x4*)(dtr + (size_t)row * NH + (col - DTOFF)) = acc[i][j];
      }
    }
  }
}

// ---------------- pipelined UV GEMM: G(f16) = (A Bu^T) .* (A Bv^T), 256x128 tile, 2-buffer ----------------
__global__ __launch_bounds__(512, 2) void gemm_uv2(
    const f16* __restrict__ A, const f16* __restrict__ Bu, const f16* __restrict__ Bv,
    f16* __restrict__ Gh)
{
  extern __shared__ char smem[];
  const int tid  = threadIdx.x;
  const int lane = tid & 63;
  const int wid  = tid >> 6;
  int bx, by; swz_tiles(bx, by);
  const int m0 = by * 256;
  const int n0 = bx * 128;
  const int NT = DIM >> 6;

  int arA[4], acA[4];
  const f16* bp[4];
  int bcB[4];
#pragma unroll
  for (int L = 0; L < 4; ++L) {
    int q = L * 512 + tid;
    int row = q >> 3;
    arA[L] = m0 + row;
    acA[L] = ((q & 7) ^ (row & 7)) << 3;
    bcB[L] = acA[L];
    bp[L] = (row < 128) ? (Bu + (size_t)(n0 + row) * DIM)
                        : (Bv + (size_t)(n0 + row - 128) * DIM);
  }

  auto stage = [&](int tt) {
    const int b = tt & 1;
    char* Ad = smem + b * 65536;
    char* Bd = Ad + 32768;
    const int kb = tt << 6;
#pragma unroll
    for (int L = 0; L < 4; ++L)
      gld16(A + (size_t)arA[L] * DIM + kb + acA[L], Ad + (L * 512 + tid) * 16);
#pragma unroll
    for (int L = 0; L < 4; ++L)
      gld16(bp[L] + kb + bcB[L], Bd + (L * 512 + tid) * 16);
  };

  const int wm = (wid >> 1) << 6;
  const int wn = (wid & 1) << 6;
  const int fr = lane & 15;
  const int kg = lane >> 4;

  f32x4 accu[4][4] = {}, accv[4][4] = {};

  stage(0);

  for (int t = 0; t < NT; ++t) {
    if (t + 1 < NT) {
      stage(t + 1);
      asm volatile("s_waitcnt vmcnt(8)" ::: "memory");
    } else {
      asm volatile("s_waitcnt vmcnt(0)" ::: "memory");
    }
    __builtin_amdgcn_s_barrier();
    asm volatile("" ::: "memory");
    const f16* Ab = (const f16*)(smem + (t & 1) * 65536);
    const f16* Bb = Ab + 16384;
#pragma unroll
    for (int s = 0; s < 2; ++s) {
      const int g = kg + s * 4;
      f16x8 af[4], bfu[4], bfv[4];
#pragma unroll
      for (int j = 0; j < 4; ++j) {
        int row = wm + j * 16 + fr;
        af[j] = *(const f16x8*)&Ab[row * 64 + ((g ^ (row & 7)) << 3)];
      }
#pragma unroll
      for (int i = 0; i < 4; ++i) {
        int ru = wn + i * 16 + fr;
        int rv = 128 + wn + i * 16 + fr;
        bfu[i] = *(const f16x8*)&Bb[ru * 64 + ((g ^ (ru & 7)) << 3)];
        bfv[i] = *(const f16x8*)&Bb[rv * 64 + ((g ^ (rv & 7)) << 3)];
      }
      __builtin_amdgcn_s_setprio(1);
#pragma unroll
      for (int i = 0; i < 4; ++i)
#pragma unroll
        for (int j = 0; j < 4; ++j) {
          accu[i][j] = __builtin_amdgcn_mfma_f32_16x16x32_f16(bfu[i], af[j], accu[i][j], 0, 0, 0);
          accv[i][j] = __builtin_amdgcn_mfma_f32_16x16x32_f16(bfv[i], af[j], accv[i][j], 0, 0, 0);
        }
      __builtin_amdgcn_s_setprio(0);
    }
    asm volatile("" ::: "memory");
    __builtin_amdgcn_s_barrier();
    asm volatile("" ::: "memory");
  }

  const int c4 = kg << 2;
#pragma unroll
  for (int i = 0; i < 4; ++i) {
    const int col = n0 + wn + i * 16 + c4;
#pragma unroll
    for (int j = 0; j < 4; ++j) {
      const int row = m0 + wm + j * 16 + fr;
      f16x4 h;
#pragma unroll
      for (int r = 0; r < 4; ++r)
        h[r] = (f16)(accu[i][j][r] * accv[i][j][r]);
      *(f16x4*)(Gh + (size_t)row * FFN + col) = h;
    }
  }
}

// fused split-K reduce + rms (parts f16)
template <bool DORMS>
__global__ __launch_bounds__(256) void reduce_rms(const f16* __restrict__ parts,
                                                  const float* __restrict__ resid,
                                                  float* __restrict__ xn,
                                                  f16* __restrict__ outh, int np)
{
  const int row = blockIdx.x, tid = threadIdx.x;
  const size_t base = (size_t)row * DIM + tid * 4;
  f32x4 s = *(const f32x4*)(resid + base);
  for (int p = 0; p < np; ++p) {
    f16x4 pv = *(const f16x4*)(parts + (size_t)p * (NTOK * DIM) + base);
#pragma unroll
    for (int c = 0; c < 4; ++c) s[c] += (float)pv[c];
  }
  if constexpr (!DORMS) {
    f16x4 h;
#pragma unroll
    for (int c = 0; c < 4; ++c) h[c] = (f16)s[c];
    *(f16x4*)(outh + base) = h;
    return;
  }
  float ss = s[0] * s[0] + s[1] * s[1] + s[2] * s[2] + s[3] * s[3];
  for (int o = 32; o; o >>= 1) ss += __shfl_down(ss, o);
  __shared__ float red[4];
  if ((tid & 63) == 0) red[tid >> 6] = ss;
  __syncthreads();
  ss = red[0] + red[1] + red[2] + red[3];
  const float sc = rsqrtf(ss * (1.f / 1024.f) + 1e-6f);
  f32x4 o4 = s * sc;
  *(f32x4*)(xn + base) = o4;
  f16x4 h;
#pragma unroll
  for (int c = 0; c < 4; ++c) h[c] = (f16)o4[c];
  *(f16x4*)(outh + base) = h;
}

// ---------------- small kernels ----------------
__global__ __launch_bounds__(256) void cvt_f2h_k(const float* __restrict__ src,
                                                 f16* __restrict__ dst, int n)
{
  for (size_t i = ((size_t)blockIdx.x * 256 + threadIdx.x) * 4; i < (size_t)n;
       i += (size_t)gridDim.x * 1024) {
    f32x4 v = *(const f32x4*)(src + i);
    f16x4 o;
#pragma unroll
    for (int c = 0; c < 4; ++c) o[c] = (f16)v[c];
    *(f16x4*)(dst + i) = o;
  }
}

// all-layer weight conversion (one dispatch, 74880 blocks)
__global__ __launch_bounds__(256) void cvt_wts(
    const float* __restrict__ inw, const float* __restrict__ outw,
    const float* __restrict__ uw, const float* __restrict__ vw,
    const float* __restrict__ ow,
    f16* __restrict__ w_in, f16* __restrict__ w_out,
    f16* __restrict__ w_uv, f16* __restrict__ w_o)
{
  const int b = blockIdx.x;
  const float* src; f16* dst;
  if (b < 17536) {
    int li = b / 4384, ib = b - li * 4384;
    src = inw  + (size_t)li * 4489216 + (size_t)ib * 1024;
    dst = w_in + (size_t)li * 4489216 + (size_t)ib * 1024;
  } else if (b < 25728) {
    int lb = b - 17536, li = lb >> 11, ib = lb & 2047;
    src = outw  + (size_t)li * 2097152 + (size_t)ib * 1024;
    dst = w_out + (size_t)li * 2097152 + (size_t)ib * 1024;
  } else if (b < 42112) {
    int lb = b - 25728, li = lb >> 12, ib = lb & 4095;
    src = uw   + (size_t)li * 4194304 + (size_t)ib * 1024;
    dst = w_uv + (size_t)li * 8388608 + (size_t)ib * 1024;
  } else if (b < 58496) {
    int lb = b - 42112, li = lb >> 12, ib = lb & 4095;
    src = vw   + (size_t)li * 4194304 + (size_t)ib * 1024;
    dst = w_uv + (size_t)li * 8388608 + 4194304 + (size_t)ib * 1024;
  } else {
    int lb = b - 58496, li = lb >> 12, ib = lb & 4095;
    src = ow  + (size_t)li * 4194304 + (size_t)ib * 1024;
    dst = w_o + (size_t)li * 4194304 + (size_t)ib * 1024;
  }
  const size_t i = (size_t)threadIdx.x * 4;
  f32x4 v = *(const f32x4*)(src + i);
  f16x4 o;
#pragma unroll
  for (int c = 0; c < 4; ++c) o[c] = (f16)v[c];
  *(f16x4*)(dst + i) = o;
}

__global__ __launch_bounds__(256) void gather_k(const int* __restrict__ tok,
                                                const float* __restrict__ emb,
                                                float* __restrict__ x)
{
  const int row = blockIdx.x;
  const int t = tok[row];
  const f32x4* s = (const f32x4*)(emb + (size_t)t * DIM);
  f32x4* d = (f32x4*)(x + (size_t)row * DIM);
  d[threadIdx.x] = s[threadIdx.x];
}

__global__ __launch_bounds__(256) void rms1024(const float* __restrict__ in,
                                               float* __restrict__ outf,
                                               f16* __restrict__ outh)
{
  const int row = blockIdx.x, tid = threadIdx.x;
  f32x4 v = ((const f32x4*)(in + (size_t)row * DIM))[tid];
  float ss = v[0] * v[0] + v[1] * v[1] + v[2] * v[2] + v[3] * v[3];
  for (int o = 32; o; o >>= 1) ss += __shfl_down(ss, o);
  __shared__ float red[4];
  if ((tid & 63) == 0) red[tid >> 6] = ss;
  __syncthreads();
  ss = red[0] + red[1] + red[2] + red[3];
  const float sc = rsqrtf(ss * (1.f / 1024.f) + 1e-6f);
  f32x4 o4 = v * sc;
  ((f32x4*)(outf + (size_t)row * DIM))[tid] = o4;
  f16x4 h;
#pragma unroll
  for (int c = 0; c < 4; ++c) h[c] = (f16)o4[c];
  ((f16x4*)(outh + (size_t)row * DIM))[tid] = h;
}

// merged conv+silu (f16 in/out) / dt+ca (f32 dtraw side-buffer)
__global__ __launch_bounds__(256) void convdt(const f16* __restrict__ zx,
                                              const float* __restrict__ dtrw,
                                              const float* __restrict__ cw,
                                              const float* __restrict__ cbias,
                                              const float* __restrict__ dtb,
                                              const float* __restrict__ alog,
                                              f16* __restrict__ xbc,
                                              float* __restrict__ dt,
                                              float* __restrict__ ca)
{
  if (blockIdx.x < 576) {
    const int sid = blockIdx.x * 256 + threadIdx.x;
    const int c0 = (sid % 576) * 4;
    const int t0 = (sid / 576) * 16;
    float w[4][4], bs[4];
#pragma unroll
    for (int cc = 0; cc < 4; ++cc) {
      f32x4 wv = *(const f32x4*)(cw + (size_t)(c0 + cc) * 4);
      w[cc][0] = wv[0]; w[cc][1] = wv[1]; w[cc][2] = wv[2]; w[cc][3] = wv[3];
      bs[cc] = cbias[c0 + cc];
    }
    const int l0 = t0 & (LSEQ - 1);
    float x3[4] = {}, x2[4] = {}, x1[4] = {};
    if (l0 != 0) {
      f16x4 a = *(const f16x4*)(zx + (size_t)(t0 - 3) * DPROJ + DIN + c0);
      f16x4 b = *(const f16x4*)(zx + (size_t)(t0 - 2) * DPROJ + DIN + c0);
      f16x4 d = *(const f16x4*)(zx + (size_t)(t0 - 1) * DPROJ + DIN + c0);
#pragma unroll
      for (int c = 0; c < 4; ++c) { x3[c] = (float)a[c]; x2[c] = (float)b[c]; x1[c] = (float)d[c]; }
    }
    for (int i = 0; i < 16; ++i) {
      const int t = t0 + i;
      f16x4 xcv = *(const f16x4*)(zx + (size_t)t * DPROJ + DIN + c0);
      f16x4 o;
#pragma unroll
      for (int cc = 0; cc < 4; ++cc) {
        float xc = (float)xcv[cc];
        float a = bs[cc] + x3[cc] * w[cc][0] + x2[cc] * w[cc][1] +
                  x1[cc] * w[cc][2] + xc * w[cc][3];
        o[cc] = (f16)(a / (1.f + expf(-a)));
        x3[cc] = x2[cc]; x2[cc] = x1[cc]; x1[cc] = xc;
      }
      *(f16x4*)(xbc + (size_t)t * CONVDIM + c0) = o;
    }
  } else {
    const int loc = (threadIdx.x >> 7) * 128;
    const int u = (blockIdx.x - 576) * 2 + (threadIdx.x >> 7);
    const int bc = u >> 5, h = u & 31, q = threadIdx.x & 127;
    const int t = bc * 128 + q;
    float raw = dtrw[(size_t)t * NH + h] + dtb[h];
    float d = raw > 20.f ? raw : log1pf(expf(raw));
    dt[t * 32 + h] = d;
    float a = -expf(alog[h]) * d;
    __shared__ float s[256];
    s[loc + q] = a;
    __syncthreads();
    for (int off = 1; off < 128; off <<= 1) {
      float v = (q >= off) ? s[loc + q - off] : 0.f;
      __syncthreads();
      s[loc + q] += v;
      __syncthreads();
    }
    ca[(size_t)u * 128 + q] = s[loc + q];
  }
}

// MFMA CB: CB[i][j] = sum_n C[i,n]*B[j,n]
__global__ __launch_bounds__(256) void cb_mfma(const f16* __restrict__ xbc,
                                               float* __restrict__ CBo)
{
  const int bc = blockIdx.x;
  __shared__ f16 Cm[128 * 72], Bm[128 * 72];
  const int tid = threadIdx.x, lane = tid & 63, wid = tid >> 6;
  const int fr = lane & 15, kg = lane >> 4;
  f32x4 acc[2][8] = {};
  const int i = tid & 127;
  const f16* rowp = xbc + (size_t)(bc * 128 + i) * CONVDIM + DIN;

  for (int kh = 0; kh < 2; ++kh) {
#pragma unroll
    for (int it = 0; it < 8; ++it) {
      int idx = it * 256 + tid;
      int n0 = (idx >> 7) * 4;
      *(f16x4*)&Bm[i * 72 + n0] = *(const f16x4*)(rowp + kh * 64 + n0);
      *(f16x4*)&Cm[i * 72 + n0] = *(const f16x4*)(rowp + DSTATE + kh * 64 + n0);
    }
    __syncthreads();
#pragma unroll
    for (int kf = 0; kf < 2; ++kf) {
      const int ko = kf * 32 + kg * 8;
      f16x8 cf[2], bf[8];
#pragma unroll
      for (int ii = 0; ii < 2; ++ii)
        cf[ii] = *(const f16x8*)&Cm[((wid * 2 + ii) * 16 + fr) * 72 + ko];
#pragma unroll
      for (int jj = 0; jj < 8; ++jj)
        bf[jj] = *(const f16x8*)&Bm[(jj * 16 + fr) * 72 + ko];
      __builtin_amdgcn_s_setprio(1);
#pragma unroll
      for (int ii = 0; ii < 2; ++ii)
#pragma unroll
        for (int jj = 0; jj < 8; ++jj)
          acc[ii][jj] = __builtin_amdgcn_mfma_f32_16x16x32_f16(cf[ii], bf[jj], acc[ii][jj], 0, 0, 0);
      __builtin_amdgcn_s_setprio(0);
    }
    __syncthreads();
  }
  float* out = CBo + (size_t)bc * 16384;
#pragma unroll
  for (int ii = 0; ii < 2; ++ii) {
    const int i0 = (wid * 2 + ii) * 16 + kg * 4;
#pragma unroll
    for (int jj = 0; jj < 8; ++jj) {
      const int j = jj * 16 + fr;
#pragma unroll
      for (int r = 0; r < 4; ++r)
        out[(size_t)(i0 + r) * 128 + j] = acc[ii][jj][r];
    }
  }
}

// MFMA states: ST[p][n] = sum_j w_j*B[j][n]*x[j][p]  (f16 output, layout [p][n])
__global__ __launch_bounds__(256) void ssd_states(const f16* __restrict__ xbc,
                                                  const float* __restrict__ dt,
                                                  const float* __restrict__ ca,
                                                  f16* __restrict__ ST)
{
  const int bc = blockIdx.x >> 5, h = blockIdx.x & 31;
  __shared__ f16 Am[128 * 136];
  __shared__ f16 Bm[64 * 136];
  __shared__ float warr[128];
  const int tid = threadIdx.x, lane = tid & 63, wid = tid >> 6;
  if (tid < 128) {
    float cv = ca[(size_t)blockIdx.x * 128 + tid];
    float cl = ca[(size_t)blockIdx.x * 128 + 127];
    warr[tid] = expf(cl - cv) * dt[(size_t)(bc * 128 + tid) * 32 + h];
  }
  __syncthreads();
  {
    const int j = tid & 127;
    const float wj = warr[j];
    const f16* br = xbc + (size_t)(bc * 128 + j) * CONVDIM + DIN;
#pragma unroll
    for (int it = 0; it < 16; ++it) {
      int idx = it * 256 + tid;
      int n0 = (idx >> 7) * 4;
      f16x4 v = *(const f16x4*)(br + n0);
#pragma unroll
      for (int c = 0; c < 4; ++c) Am[(n0 + c) * 136 + j] = (f16)((float)v[c] * wj);
    }
    const f16* xr = xbc + (size_t)(bc * 128 + j) * CONVDIM + h * 64;
#pragma unroll
    for (int it = 0; it < 8; ++it) {
      int idx = it * 256 + tid;
      int p0 = (idx >> 7) * 4;
      f16x4 v = *(const f16x4*)(xr + p0);
#pragma unroll
      for (int c = 0; c < 4; ++c) Bm[(p0 + c) * 136 + j] = v[c];
    }
  }
  __syncthreads();
  const int fr = lane & 15, kg = lane >> 4;
  f32x4 acc[2][4] = {};
#pragma unroll
  for (int kf = 0; kf < 4; ++kf) {
    const int ko = kf * 32 + kg * 8;
    f16x8 bw[2], xf[4];
#pragma unroll
    for (int ii = 0; ii < 2; ++ii)
      bw[ii] = *(const f16x8*)&Am[((wid * 2 + ii) * 16 + fr) * 136 + ko];
#pragma unroll
    for (int pi = 0; pi < 4; ++pi)
      xf[pi] = *(const f16x8*)&Bm[(pi * 16 + fr) * 136 + ko];
    __builtin_amdgcn_s_setprio(1);
#pragma unroll
    for (int ii = 0; ii < 2; ++ii)
#pragma unroll
      for (int pi = 0; pi < 4; ++pi)
        acc[ii][pi] = __builtin_amdgcn_mfma_f32_16x16x32_f16(bw[ii], xf[pi], acc[ii][pi], 0, 0, 0);
    __builtin_amdgcn_s_setprio(0);
  }
  f16* sb = ST + (size_t)blockIdx.x * 8192;
#pragma unroll
  for (int ii = 0; ii < 2; ++ii) {
    const int n0 = (wid * 2 + ii) * 16 + kg * 4;
#pragma unroll
    for (int pi = 0; pi < 4; ++pi) {
      const int p = pi * 16 + fr;
      f16x4 hv;
#pragma unroll
      for (int c = 0; c < 4; ++c) hv[c] = (f16)acc[ii][pi][c];
      *(f16x4*)(sb + (size_t)p * 128 + n0) = hv;
    }
  }
}

// inter-chunk scan (f16 states; f32 running accumulator in registers)
__global__ __launch_bounds__(256) void scan_k(const float* __restrict__ ca,
                                              f16* __restrict__ states)
{
  const int b = blockIdx.x >> 10, h = (blockIdx.x >> 5) & 31, seg = blockIdx.x & 31;
  const int e = seg * 256 + threadIdx.x;
  float s = 0.f;
  for (int c = 0; c < CPB; ++c) {
    int bc = b * CPB + c;
    float cd = expf(ca[(size_t)(bc * 32 + h) * 128 + 127]);
    size_t idx = (size_t)(bc * 32 + h) * 8192 + e;
    float v = (float)states[idx];
    states[idx] = (f16)s;
    s = s * cd + v;
  }
}

// MFMA fused y = T@XD + exp(ca)*(C@ST^T) + D*x  (f16 ST direct staging)
__global__ __launch_bounds__(256) void ssd_y(const f16* __restrict__ xbc,
                                             const float* __restrict__ dt,
                                             const float* __restrict__ ca,
                                             const float* __restrict__ CB,
                                             const float* __restrict__ Dvec,
                                             const f16* __restrict__ ST,
                                             f16* __restrict__ ybuf)
{
  const int bc = blockIdx.x >> 5, h = blockIdx.x & 31;
  __shared__ f16 Am[128 * 136];
  __shared__ f16 Bm[64 * 136];
  __shared__ float cas[128], dtl[128];
  const int tid = threadIdx.x, lane = tid & 63, wid = tid >> 6;
  if (tid < 128) {
    cas[tid] = ca[(size_t)blockIdx.x * 128 + tid];
    dtl[tid] = dt[(size_t)(bc * 128 + tid) * 32 + h];
  }
  __syncthreads();
  {
    const int j = tid & 127;
    const float dj = dtl[j];
    const f16* xr = xbc + (size_t)(bc * 128 + j) * CONVDIM + h * 64;
#pragma unroll
    for (int it = 0; it < 8; ++it) {
      int idx = it * 256 + tid;
      int p0 = (idx >> 7) * 4;
      f16x4 v = *(const f16x4*)(xr + p0);
#pragma unroll
      for (int c = 0; c < 4; ++c) Bm[(p0 + c) * 136 + j] = (f16)((float)v[c] * dj);
    }
  }
  {
    const int i = tid >> 1;
    const int jh = (tid & 1) * 64;
    const float cai = cas[i];
    const float* cbr = CB + (size_t)bc * 16384 + (size_t)i * 128 + jh;
#pragma unroll
    for (int g = 0; g < 8; ++g) {
      int j0 = g * 8;
      f32x4 v0 = *(const f32x4*)(cbr + j0);
      f32x4 v1 = *(const f32x4*)(cbr + j0 + 4);
      f16x8 tv;
#pragma unroll
      for (int c = 0; c < 8; ++c) {
        int j = jh + j0 + c;
        float cbv = (c < 4) ? v0[c] : v1[c - 4];
        float val = (j <= i) ? cbv * expf(cai - cas[j]) : 0.f;
        tv[c] = (f16)val;
      }
      *(f16x8*)&Am[i * 136 + jh + j0] = tv;
    }
  }
  __syncthreads();
  const int fr = lane & 15, kg = lane >> 4;
  f32x4 a1[2][4] = {}, a2[2][4] = {};
#pragma unroll
  for (int kf = 0; kf < 4; ++kf) {
    const int ko = kf * 32 + kg * 8;
    f16x8 xf[4], tf[2];
#pragma unroll
    for (int pi = 0; pi < 4; ++pi)
      xf[pi] = *(const f16x8*)&Bm[(pi * 16 + fr) * 136 + ko];
#pragma unroll
    for (int ii = 0; ii < 2; ++ii)
      tf[ii] = *(const f16x8*)&Am[((wid * 2 + ii) * 16 + fr) * 136 + ko];
    __builtin_amdgcn_s_setprio(1);
#pragma unroll
    for (int ii = 0; ii < 2; ++ii)
#pragma unroll
      for (int pi = 0; pi < 4; ++pi)
        a1[ii][pi] = __builtin_amdgcn_mfma_f32_16x16x32_f16(xf[pi], tf[ii], a1[ii][pi], 0, 0, 0);
    __builtin_amdgcn_s_setprio(0);
  }
  __syncthreads();
  {
    const int i = tid & 127;
    const f16* cr = xbc + (size_t)(bc * 128 + i) * CONVDIM + DIN + DSTATE;
#pragma unroll
    for (int it = 0; it < 16; ++it) {
      int idx = it * 256 + tid;
      int n0 = (idx >> 7) * 4;
      *(f16x4*)&Am[i * 136 + n0] = *(const f16x4*)(cr + n0);
    }
    const f16* sr = ST + (size_t)blockIdx.x * 8192;
    const int p = tid & 63;
#pragma unroll
    for (int it = 0; it < 8; ++it) {
      int idx = it * 256 + tid;
      int n0 = (idx >> 6) * 4;
      *(f16x4*)&Bm[p * 136 + n0] = *(const f16x4*)(sr + (size_t)p * 128 + n0);
    }
  }
  __syncthreads();
#pragma unroll
  for (int kf = 0; kf < 4; ++kf) {
    const int ko = kf * 32 + kg * 8;
    f16x8 sf[4], cf[2];
#pragma unroll
    for (int pi = 0; pi < 4; ++pi)
      sf[pi] = *(const f16x8*)&Bm[(pi * 16 + fr) * 136 + ko];
#pragma unroll
    for (int ii = 0; ii < 2; ++ii)
      cf[ii] = *(const f16x8*)&Am[((wid * 2 + ii) * 16 + fr) * 136 + ko];
    __builtin_amdgcn_s_setprio(1);
#pragma unroll
    for (int ii = 0; ii < 2; ++ii)
#pragma unroll
      for (int pi = 0; pi < 4; ++pi)
        a2[ii][pi] = __builtin_amdgcn_mfma_f32_16x16x32_f16(sf[pi], cf[ii], a2[ii][pi], 0, 0, 0);
    __builtin_amdgcn_s_setprio(0);
  }
  const float dh = Dvec[h];
#pragma unroll
  for (int ii = 0; ii < 2; ++ii) {
    const int i = (wid * 2 + ii) * 16 + fr;
    const float ei = expf(cas[i]);
    const int tg = bc * 128 + i;
#pragma unroll
    for (int pi = 0; pi < 4; ++pi) {
      const int p0 = pi * 16 + kg * 4;
      f16x4 xv = *(const f16x4*)(xbc + (size_t)tg * CONVDIM + h * 64 + p0);
      f16x4 yo;
#pragma unroll
      for (int r = 0; r < 4; ++r)
        yo[r] = (f16)(a1[ii][pi][r] + ei * a2[ii][pi][r] + dh * (float)xv[r]);
      *(f16x4*)(ybuf + (size_t)tg * DIN + h * 64 + p0) = yo;
    }
  }
}

// yg = y*silu(z); rms(2048) * mnorm_w -> fp16
__global__ __launch_bounds__(256) void gate_rms(const f16* __restrict__ ybuf,
                                                const f16* __restrict__ zx,
                                                const float* __restrict__ nw,
                                                f16* __restrict__ outh)
{
  const int row = blockIdx.x, tid = threadIdx.x;
  f16x8 yv = *(const f16x8*)(ybuf + (size_t)row * DIN + tid * 8);
  f16x8 zv = *(const f16x8*)(zx + (size_t)row * DPROJ + tid * 8);
  float g[8];
  float ss = 0.f;
#pragma unroll
  for (int c = 0; c < 8; ++c) {
    float z = (float)zv[c];
    g[c] = (float)yv[c] * (z / (1.f + expf(-z)));
    ss += g[c] * g[c];
  }
  for (int o = 32; o; o >>= 1) ss += __shfl_down(ss, o);
  __shared__ float red[4];
  if ((tid & 63) == 0) red[tid >> 6] = ss;
  __syncthreads();
  ss = red[0] + red[1] + red[2] + red[3];
  const float sc = rsqrtf(ss * (1.f / 2048.f) + 1e-6f);
  f32x4 w0 = *(const f32x4*)(nw + tid * 8);
  f32x4 w1 = *(const f32x4*)(nw + tid * 8 + 4);
  f16x8 h;
#pragma unroll
  for (int c = 0; c < 8; ++c) {
    float w = (c < 4) ? w0[c] : w1[c - 4];
    h[c] = (f16)(g[c] * sc * w);
  }
  *(f16x8*)(outh + (size_t)row * DIN + tid * 8) = h;
}

// ---------------- launcher ----------------
extern "C" void kernel_launch(void* const* d_in, const int* in_sizes, int n_in,
                              void* d_out, int out_size, void* d_ws, size_t ws_size,
                              hipStream_t stream)
{
  (void)in_sizes; (void)n_in; (void)out_size; (void)ws_size;
  const int*   tokens = (const int*)d_in[0];
  const float* emb    = (const float*)d_in[1];
  const float* lmb    = (const float*)d_in[2];
  const float* inw    = (const float*)d_in[3];
  const float* cw     = (const float*)d_in[4];
  const float* cbias  = (const float*)d_in[5];
  const float* dtb    = (const float*)d_in[6];
  const float* alog   = (const float*)d_in[7];
  const float* Dvec   = (const float*)d_in[8];
  const float* nw     = (const float*)d_in[9];
  const float* outw   = (const float*)d_in[10];
  const float* uw     = (const float*)d_in[11];
  const float* vw     = (const float*)d_in[12];
  const float* ow     = (const float*)d_in[13];

  char* ws = (char*)d_ws;
  size_t off = 0;
  auto alloc = [&](size_t bytes) { void* p = ws + off; off += (bytes + 255) & ~(size_t)255; return p; };
  f16* emb_h   = (f16*)alloc((size_t)VOCAB * DIM * 2);
  float* xbuf  = (float*)alloc((size_t)NTOK * DIM * 4);
  float* xn    = (float*)alloc((size_t)NTOK * DIM * 4);
  f16* xnh     = (f16*)alloc((size_t)NTOK * DIM * 2);
  f16* xh_lm   = (f16*)alloc((size_t)NTOK * DIM * 2);
  float* dtraw = (float*)alloc((size_t)NTOK * NH * 4);
  float* dtbuf = (float*)alloc((size_t)NTOK * NH * 4);
  float* cabuf = (float*)alloc((size_t)NCHUNK * NH * QLEN * 4);
  float* CBbuf = (float*)alloc((size_t)NCHUNK * QLEN * QLEN * 4);
  f16* abh     = (f16*)alloc((size_t)NTOK * FFN * 2);

  // d_out transients + converted weights (all overwritten by final lm-head GEMM)
  char* ob = (char*)d_out;
  f16* states   = (f16*)(ob);                        // 16.8 MB (f16)
  f16* zxb      = (f16*)(ob + 40000000);
  f16* xbc      = (f16*)(ob + 80000000);
  f16* ybuf     = (f16*)(ob + 100000000);
  f16* parts    = (f16*)(ob + 120000000);
  f16* w_in     = (f16*)(ob + 160000000);
  f16* w_out    = (f16*)(ob + 196000000);
  f16* w_uv     = (f16*)(ob + 213000000);
  f16* w_o      = (f16*)(ob + 281000000);

  cvt_f2h_k<<<4096, 256, 0, stream>>>(emb, emb_h, VOCAB * DIM);
  cvt_wts<<<74880, 256, 0, stream>>>(inw, outw, uw, vw, ow, w_in, w_out, w_uv, w_o);
  gather_k<<<NTOK, 256, 0, stream>>>(tokens, emb, xbuf);
  rms1024<<<NTOK, 256, 0, stream>>>(xbuf, xn, xnh);

  for (int it = 0; it < 2 * NLAYER; ++it) {
    const int li = it >> 1;
    const f16* w_inL  = w_in  + (size_t)li * 4489216;
    const f16* w_outL = w_out + (size_t)li * 2097152;
    const f16* w_uL   = w_uv  + (size_t)li * 8388608;
    const f16* w_vL   = w_uL  + 4194304;
    const f16* w_oL   = w_o   + (size_t)li * 4194304;
    // mamba
    gemm_p<0><<<dim3((DPROJ + 127) / 128, NTOK / 256, 1), 512, SMEM_BYTES, stream>>>(
        xnh, w_inL, zxb, nullptr, dtraw, nullptr, DPROJ, DIM, DIM, DIM, DPROJ);
    convdt<<<1088, 256, 0, stream>>>(zxb, dtraw, cw + (size_t)li * CONVDIM * DCONV,
                                     cbias + (size_t)li * CONVDIM,
                                     dtb + li * NH, alog + li * NH, xbc, dtbuf, cabuf);
    cb_mfma<<<NCHUNK, 256, 0, stream>>>(xbc, CBbuf);
    ssd_states<<<NCHUNK * NH, 256, 0, stream>>>(xbc, dtbuf, cabuf, states);
    scan_k<<<2048, 256, 0, stream>>>(cabuf, states);
    ssd_y<<<NCHUNK * NH, 256, 0, stream>>>(xbc, dtbuf, cabuf, CBbuf,
                                           Dvec + li * NH, states, ybuf);
    gate_rms<<<NTOK, 256, 0, stream>>>(ybuf, zxb, nw + (size_t)li * DIN, abh);
    // out_proj: split-K x2 -> f16 parts; fused reduce(+resid) + rms
    gemm_p<0><<<dim3(DIM / 128, NTOK / 256, 2), 512, SMEM_BYTES, stream>>>(
        abh, w_outL, parts, nullptr, nullptr, nullptr, DIM, DIN / 2, DIN, DIN, DIM);
    reduce_rms<true><<<NTOK, 256, 0, stream>>>(parts, xn, xn, xnh, 2);
    // gated FFN
    gemm_uv2<<<dim3(FFN / 128, NTOK / 256, 1), 512, SMEM2, stream>>>(
        xnh, w_uL, w_vL, abh);
    // o_proj: split-K x2
    gemm_p<0><<<dim3(DIM / 128, NTOK / 256, 2), 512, SMEM_BYTES, stream>>>(
        abh, w_oL, parts, nullptr, nullptr, nullptr, DIM, FFN / 2, FFN, FFN, DIM);
    if (it < 2 * NLAYER - 1)
      reduce_rms<true><<<NTOK, 256, 0, stream>>>(parts, xn, xn, xnh, 2);
    else
      reduce_rms<false><<<NTOK, 256, 0, stream>>>(parts, xn, nullptr, xh_lm, 2);
  }

  // lm head (MODE 1: f32 out + bias)
  gemm_p<1><<<dim3(VOCAB / 128, NTOK / 256, 1), 512, SMEM_BYTES, stream>>>(
      xh_lm, emb_h, nullptr, (float*)d_out, nullptr, lmb, VOCAB, DIM, DIM, DIM, VOCAB);
}